// Round 5
// baseline (595.099 us; speedup 1.0000x reference)
//
#include <hip/hip_runtime.h>
#include <cstdint>

#define F 64
#define NPB 128        // nodes per matvec block
#define SCAN_BLK 1024
#define SORT_NODES 1024
#define BINS 64

// ---------------------------------------------------------------------------
// helpers: bf16 <-> fp32
// ---------------------------------------------------------------------------
__device__ __forceinline__ unsigned short f2b(float f) {     // RNE round
    unsigned u = __float_as_uint(f);
    unsigned r = u + 0x7fffu + ((u >> 16) & 1u);
    return (unsigned short)(r >> 16);
}
__device__ __forceinline__ float4 b2f4(uint2 u) {
    return make_float4(__uint_as_float(u.x << 16),
                       __uint_as_float(u.x & 0xffff0000u),
                       __uint_as_float(u.y << 16),
                       __uint_as_float(u.y & 0xffff0000u));
}

// ---------------------------------------------------------------------------
// Degree count (4 edges/thread for MLP)
// ---------------------------------------------------------------------------
__global__ __launch_bounds__(256) void count_kernel(
    const int* __restrict__ dst, int* __restrict__ deg, int E) {
    int i = (blockIdx.x * 256 + threadIdx.x) * 4;
    if (i + 3 < E) {
        int4 d4 = *(const int4*)(dst + i);
        atomicAdd(&deg[d4.x], 1);
        atomicAdd(&deg[d4.y], 1);
        atomicAdd(&deg[d4.z], 1);
        atomicAdd(&deg[d4.w], 1);
    } else {
        for (int e = i; e < E; ++e) atomicAdd(&deg[dst[e]], 1);
    }
}

// ---------------------------------------------------------------------------
// Counting sort of nodes by degree (distributed, 64 bins).
// sort_hist: per-block LDS histogram -> binMat[bin * nbs + blk]
// sort_scan: exclusive scan of binMat (bin-major) in one block
// sort_scatter: pos = binMat prefix + local rank; perm[pos]=node
// ---------------------------------------------------------------------------
__global__ __launch_bounds__(256) void sort_hist_kernel(
    const int* __restrict__ deg, int* __restrict__ binMat, int n, int nbs) {
    __shared__ int lh[BINS];
    int t = threadIdx.x;
    if (t < BINS) lh[t] = 0;
    __syncthreads();
    int base = blockIdx.x * SORT_NODES;
#pragma unroll
    for (int k = 0; k < 4; ++k) {
        int i = base + k * 256 + t;
        if (i < n) atomicAdd(&lh[min(deg[i], BINS - 1)], 1);
    }
    __syncthreads();
    if (t < BINS) binMat[t * nbs + blockIdx.x] = lh[t];
}

__global__ __launch_bounds__(SCAN_BLK) void sort_scan_kernel(
    int* __restrict__ binMat, int len) {
    __shared__ int sh[SCAN_BLK];
    int t = threadIdx.x;
    int ch = (len + SCAN_BLK - 1) / SCAN_BLK;   // <= 8
    int b0 = t * ch;
    int loc[8];
    int lsum = 0;
    for (int k = 0; k < ch; ++k) {
        int i = b0 + k;
        int v = (i < len) ? binMat[i] : 0;
        loc[k] = lsum;
        lsum += v;
    }
    sh[t] = lsum;
    __syncthreads();
    for (int off = 1; off < SCAN_BLK; off <<= 1) {
        int add = (t >= off) ? sh[t - off] : 0;
        __syncthreads();
        sh[t] += add;
        __syncthreads();
    }
    int tex = sh[t] - lsum;
    for (int k = 0; k < ch; ++k) {
        int i = b0 + k;
        if (i < len) binMat[i] = tex + loc[k];
    }
}

__global__ __launch_bounds__(256) void sort_scatter_kernel(
    const int* __restrict__ deg, const int* __restrict__ binMat,
    int* __restrict__ perm, int* __restrict__ degPerm, int n, int nbs) {
    __shared__ int lh[BINS];
    int t = threadIdx.x;
    if (t < BINS) lh[t] = binMat[t * nbs + blockIdx.x];
    __syncthreads();
    int base = blockIdx.x * SORT_NODES;
#pragma unroll
    for (int k = 0; k < 4; ++k) {
        int i = base + k * 256 + t;
        if (i < n) {
            int d = deg[i];
            int pos = atomicAdd(&lh[min(d, BINS - 1)], 1);
            perm[pos] = i;
            degPerm[pos] = d;
        }
    }
}

// ---------------------------------------------------------------------------
// Exclusive scan of degPerm -> rowStartPerm (+ cursor init by original node)
// ---------------------------------------------------------------------------
__global__ __launch_bounds__(SCAN_BLK) void scan_blocks_kernel(
    const int* __restrict__ deg, int* __restrict__ ex,
    int* __restrict__ blockSums, int n) {
    __shared__ int sh[SCAN_BLK];
    int t = threadIdx.x;
    int i = blockIdx.x * SCAN_BLK + t;
    int v = (i < n) ? deg[i] : 0;
    sh[t] = v;
    __syncthreads();
    for (int off = 1; off < SCAN_BLK; off <<= 1) {
        int add = (t >= off) ? sh[t - off] : 0;
        __syncthreads();
        sh[t] += add;
        __syncthreads();
    }
    int incl = sh[t];
    if (i < n) ex[i] = incl - v;
    if (t == SCAN_BLK - 1) blockSums[blockIdx.x] = incl;
}

__global__ __launch_bounds__(SCAN_BLK) void scan_sums_kernel(
    int* __restrict__ blockSums, int nb) {
    __shared__ int sh[SCAN_BLK];
    int t = threadIdx.x;
    int v = (t < nb) ? blockSums[t] : 0;
    sh[t] = v;
    __syncthreads();
    for (int off = 1; off < SCAN_BLK; off <<= 1) {
        int add = (t >= off) ? sh[t - off] : 0;
        __syncthreads();
        sh[t] += add;
        __syncthreads();
    }
    if (t < nb) blockSums[t] = sh[t] - v;
}

__global__ __launch_bounds__(256) void add_offsets2_kernel(
    int* __restrict__ ex, const int* __restrict__ blockSums,
    const int* __restrict__ perm, int* __restrict__ cursor, int n, int E) {
    int i = blockIdx.x * 256 + threadIdx.x;
    if (i < n) {
        int v = ex[i] + blockSums[i >> 10];
        ex[i] = v;
        cursor[perm[i]] = v;
    }
    if (i == 0) ex[n] = E;
}

// ---------------------------------------------------------------------------
// Fill permuted CSR (4 edges/thread for MLP)
// ---------------------------------------------------------------------------
__global__ __launch_bounds__(256) void fill_kernel(
    const int* __restrict__ src, const int* __restrict__ dst,
    int* __restrict__ cursor, int* __restrict__ csrSrc, int E) {
    int i = (blockIdx.x * 256 + threadIdx.x) * 4;
    if (i + 3 < E) {
        int4 s4 = *(const int4*)(src + i);
        int4 d4 = *(const int4*)(dst + i);
        int p0 = atomicAdd(&cursor[d4.x], 1);
        int p1 = atomicAdd(&cursor[d4.y], 1);
        int p2 = atomicAdd(&cursor[d4.z], 1);
        int p3 = atomicAdd(&cursor[d4.w], 1);
        csrSrc[p0] = s4.x;
        csrSrc[p1] = s4.y;
        csrSrc[p2] = s4.z;
        csrSrc[p3] = s4.w;
    } else {
        for (int e = i; e < E; ++e) {
            int p = atomicAdd(&cursor[dst[e]], 1);
            csrSrc[p] = src[e];
        }
    }
}

// ---------------------------------------------------------------------------
// Prep: weight swizzle (blocks 0..23) + x -> bf16 (remaining blocks).
// ---------------------------------------------------------------------------
__global__ __launch_bounds__(256) void prep_kernel(
    const float* __restrict__ Wl0, const float* __restrict__ Wr0,
    const float* __restrict__ Wl1, const float* __restrict__ Wr1,
    const float* __restrict__ Wl2, const float* __restrict__ Wr2,
    float4* __restrict__ WSw,
    const float* __restrict__ x, ushort* __restrict__ xb, int nElem) {
    int b = blockIdx.x;
    int t = threadIdx.x;
    if (b < 24) {
        int g = b * 256 + t;
        if (g >= 3 * 2048) return;
        int set = g >> 11;
        int r = g & 2047;
        int m = r >> 10;
        int q = r & 1023;
        int f4 = q >> 6;
        int kk = (q >> 4) & 3;
        int oc = q & 15;
        const float* W = (set == 0) ? (m ? Wr0 : Wl0)
                       : (set == 1) ? (m ? Wr1 : Wl1)
                                    : (m ? Wr2 : Wl2);
        const float4* W4 = (const float4*)W;
        WSw[g] = W4[(4 * oc + kk) * (F / 4) + f4];
    } else {
        int i = (b - 24) * 256 + t;
        int n4 = nElem >> 2;
        if (i < n4) {
            float4 v = ((const float4*)x)[i];
            uint2 o;
            o.x = (unsigned)f2b(v.x) | ((unsigned)f2b(v.y) << 16);
            o.y = (unsigned)f2b(v.z) | ((unsigned)f2b(v.w) << 16);
            ((uint2*)xb)[i] = o;
        }
    }
}

// ---------------------------------------------------------------------------
// Gather over permuted node index r (degree-uniform waves, contiguous CSR).
// 8 lanes/node; also copies self row into permuted contiguous selfPerm.
// ---------------------------------------------------------------------------
__device__ __forceinline__ void add8(float* a, uint4 u) {
    const unsigned* p = (const unsigned*)&u;
#pragma unroll
    for (int i = 0; i < 4; ++i) {
        a[2 * i + 0] += __uint_as_float(p[i] << 16);
        a[2 * i + 1] += __uint_as_float(p[i] & 0xffff0000u);
    }
}

__global__ __launch_bounds__(256, 8) void gather_kernel(
    const ushort* __restrict__ hb, const int* __restrict__ rowStartPerm,
    const int* __restrict__ csrSrc, const int* __restrict__ perm,
    float* __restrict__ agg, ushort* __restrict__ selfPerm, int n) {
    int gid = blockIdx.x * 256 + threadIdx.x;
    int r = gid >> 3;
    int c = gid & 7;
    if (r >= n) return;

    const uint4* h16 = (const uint4*)hb;
    float a[8] = {0.f, 0.f, 0.f, 0.f, 0.f, 0.f, 0.f, 0.f};

    int e = rowStartPerm[r];
    int end = rowStartPerm[r + 1];
    for (; e + 3 < end; e += 4) {
        int s0 = csrSrc[e + 0];
        int s1 = csrSrc[e + 1];
        int s2 = csrSrc[e + 2];
        int s3 = csrSrc[e + 3];
        uint4 u0 = h16[(size_t)s0 * 8 + c];
        uint4 u1 = h16[(size_t)s1 * 8 + c];
        uint4 u2 = h16[(size_t)s2 * 8 + c];
        uint4 u3 = h16[(size_t)s3 * 8 + c];
        add8(a, u0); add8(a, u1); add8(a, u2); add8(a, u3);
    }
    for (; e < end; ++e) {
        uint4 u0 = h16[(size_t)csrSrc[e] * 8 + c];
        add8(a, u0);
    }

    float4* o = (float4*)(agg + (size_t)r * F);
    o[2 * c + 0] = make_float4(a[0], a[1], a[2], a[3]);
    o[2 * c + 1] = make_float4(a[4], a[5], a[6], a[7]);

    int node = perm[r];
    ((uint4*)selfPerm)[(size_t)r * 8 + c] = h16[(size_t)node * 8 + c];
}

// ---------------------------------------------------------------------------
// Matvec over permuted rows; output scattered to original node ids via perm.
// flags: bit0 = tanh, bit1 = bf16 output.
// ---------------------------------------------------------------------------
__global__ __launch_bounds__(256, 2) void matvec_kernel(
    const float* __restrict__ agg, const ushort* __restrict__ selfPerm,
    const int* __restrict__ perm,
    const float4* __restrict__ WSwSet, const float* __restrict__ bl,
    void* __restrict__ out, int n, int flags) {
    __shared__ float4 WT[2048];       // 32 KB swizzled [Wl;Wr]
    __shared__ float4 aggT[NPB * 16]; // 32 KB

    int t = threadIdx.x;
    int node0 = blockIdx.x * NPB;

#pragma unroll
    for (int i = 0; i < 8; ++i) WT[t + 256 * i] = WSwSet[t + 256 * i];

    const float4* aggG = (const float4*)agg + (size_t)node0 * 16;
#pragma unroll
    for (int k = 0; k < 8; ++k) {
        int idx = k * 256 + t;
        int nn = idx >> 4;
        int f4 = idx & 15;
        aggT[nn * 16 + (f4 ^ ((nn >> 3) & 15))] = aggG[idx];
    }
    __syncthreads();

    int w = t >> 6;
    int lane = t & 63;
    int ng = lane >> 4;
    int oc = lane & 15;
    int nbase = w * 32 + ng * 8;
    int sw = (nbase >> 3) & 15;

    float4 b4 = ((const float4*)bl)[oc];
    float4 acc[8];
#pragma unroll
    for (int j = 0; j < 8; ++j) acc[j] = b4;

    // agg @ Wl
#pragma unroll 4
    for (int f4 = 0; f4 < 16; ++f4) {
        float4 w0 = WT[f4 * 64 + oc];
        float4 w1 = WT[f4 * 64 + 16 + oc];
        float4 w2 = WT[f4 * 64 + 32 + oc];
        float4 w3 = WT[f4 * 64 + 48 + oc];
        int slot = f4 ^ sw;
#pragma unroll
        for (int j = 0; j < 8; ++j) {
            float4 a = aggT[(nbase + j) * 16 + slot];
            acc[j].x += a.x * w0.x + a.y * w0.y + a.z * w0.z + a.w * w0.w;
            acc[j].y += a.x * w1.x + a.y * w1.y + a.z * w1.z + a.w * w1.w;
            acc[j].z += a.x * w2.x + a.y * w2.y + a.z * w2.z + a.w * w2.w;
            acc[j].w += a.x * w3.x + a.y * w3.y + a.z * w3.z + a.w * w3.w;
        }
    }

    // self @ Wr (contiguous permuted bf16, block tile L1-resident)
    const uint2* hb2 = (const uint2*)selfPerm + (size_t)node0 * 16;
#pragma unroll 4
    for (int f4 = 0; f4 < 16; ++f4) {
        float4 w0 = WT[1024 + f4 * 64 + oc];
        float4 w1 = WT[1024 + f4 * 64 + 16 + oc];
        float4 w2 = WT[1024 + f4 * 64 + 32 + oc];
        float4 w3 = WT[1024 + f4 * 64 + 48 + oc];
#pragma unroll
        for (int j = 0; j < 8; ++j) {
            float4 a = b2f4(hb2[(nbase + j) * 16 + f4]);
            acc[j].x += a.x * w0.x + a.y * w0.y + a.z * w0.z + a.w * w0.w;
            acc[j].y += a.x * w1.x + a.y * w1.y + a.z * w1.z + a.w * w1.w;
            acc[j].z += a.x * w2.x + a.y * w2.y + a.z * w2.z + a.w * w2.w;
            acc[j].w += a.x * w3.x + a.y * w3.y + a.z * w3.z + a.w * w3.w;
        }
    }

#pragma unroll
    for (int j = 0; j < 8; ++j) {
        int rr = node0 + nbase + j;
        if (rr < n) {
            int onode = perm[rr];
            float4 v = acc[j];
            if (flags & 1) {
                v.x = tanhf(v.x); v.y = tanhf(v.y);
                v.z = tanhf(v.z); v.w = tanhf(v.w);
            }
            if (flags & 2) {
                uint2 o;
                o.x = (unsigned)f2b(v.x) | ((unsigned)f2b(v.y) << 16);
                o.y = (unsigned)f2b(v.z) | ((unsigned)f2b(v.w) << 16);
                ((uint2*)out)[(size_t)onode * 16 + oc] = o;
            } else {
                ((float4*)out)[(size_t)onode * 16 + oc] = v;
            }
        }
    }
}

// ---------------------------------------------------------------------------
// Launch
// ---------------------------------------------------------------------------
extern "C" void kernel_launch(void* const* d_in, const int* in_sizes, int n_in,
                              void* d_out, int out_size, void* d_ws, size_t ws_size,
                              hipStream_t stream) {
    const float* x      = (const float*)d_in[0];
    const int*   edges  = (const int*)d_in[1];
    const float* Wl_in  = (const float*)d_in[2];
    const float* bl_in  = (const float*)d_in[3];
    const float* Wr_in  = (const float*)d_in[4];
    const float* Wl_med = (const float*)d_in[5];
    const float* bl_med = (const float*)d_in[6];
    const float* Wr_med = (const float*)d_in[7];
    const float* Wl_out = (const float*)d_in[8];
    const float* bl_out = (const float*)d_in[9];
    const float* Wr_out = (const float*)d_in[10];

    const int N = in_sizes[0] / F;
    const int E = in_sizes[1] / 2;
    const int* src = edges;
    const int* dst = edges + E;

    const int NR = ((N + NPB - 1) / NPB) * NPB;   // rounded for tile loads
    const int nbs = (N + SORT_NODES - 1) / SORT_NODES;

    // Workspace layout (16B-aligned chunks)
    float4* WSw      = (float4*)d_ws;                       // 6144 float4
    float*  agg      = (float*)(WSw + 6144);                // NR*F fp32
    ushort* selfPerm = (ushort*)(agg + (size_t)NR * F);     // NR*F bf16
    ushort* xb       = selfPerm + (size_t)NR * F;           // N*F bf16
    ushort* hAb      = xb + (size_t)N * F;                  // N*F bf16
    ushort* hBb      = hAb + (size_t)N * F;                 // N*F bf16
    int* rowStartPerm = (int*)(hBb + (size_t)N * F);        // N+1
    int* degPerm      = rowStartPerm + (N + 1);             // N
    int* deg          = degPerm + N;                        // N
    int* cursor       = deg + N;                            // N
    int* perm         = cursor + N;                         // N
    int* blockSums    = perm + N;                           // SCAN_BLK
    int* binMat       = blockSums + SCAN_BLK;               // BINS*nbs
    int* csrSrc       = binMat + BINS * nbs;                // E

    const int eb4 = (E / 4 + 255) / 256;
    const int gather_blocks = (N * 8 + 255) / 256;
    const int mv_blocks = NR / NPB;
    const int prep_blocks = 24 + (N * F / 4 + 255) / 256;
    const int nb_scan = (N + SCAN_BLK - 1) / SCAN_BLK;

    // Prep (weights + x->bf16)
    prep_kernel<<<prep_blocks, 256, 0, stream>>>(Wl_in, Wr_in, Wl_med, Wr_med,
                                                 Wl_out, Wr_out, WSw, x, xb, N * F);

    // Degree count
    hipMemsetAsync(deg, 0, (size_t)N * sizeof(int), stream);
    count_kernel<<<eb4, 256, 0, stream>>>(dst, deg, E);

    // Counting sort of nodes by degree
    sort_hist_kernel<<<nbs, 256, 0, stream>>>(deg, binMat, N, nbs);
    sort_scan_kernel<<<1, SCAN_BLK, 0, stream>>>(binMat, BINS * nbs);
    sort_scatter_kernel<<<nbs, 256, 0, stream>>>(deg, binMat, perm, degPerm, N, nbs);

    // rowStartPerm = scan(degPerm); cursor[origNode] = rowStartPerm[rank]
    scan_blocks_kernel<<<nb_scan, SCAN_BLK, 0, stream>>>(degPerm, rowStartPerm, blockSums, N);
    scan_sums_kernel<<<1, SCAN_BLK, 0, stream>>>(blockSums, nb_scan);
    add_offsets2_kernel<<<(N + 255) / 256, 256, 0, stream>>>(rowStartPerm, blockSums, perm, cursor, N, E);

    // Fill permuted CSR
    fill_kernel<<<eb4, 256, 0, stream>>>(src, dst, cursor, csrSrc, E);

    // Layer 1: xb -> hAb (tanh, bf16 out)
    gather_kernel<<<gather_blocks, 256, 0, stream>>>(xb, rowStartPerm, csrSrc, perm, agg, selfPerm, N);
    matvec_kernel<<<mv_blocks, 256, 0, stream>>>(agg, selfPerm, perm, WSw + 0, bl_in, hAb, N, 3);
    // Layer 2: hAb -> hBb
    gather_kernel<<<gather_blocks, 256, 0, stream>>>(hAb, rowStartPerm, csrSrc, perm, agg, selfPerm, N);
    matvec_kernel<<<mv_blocks, 256, 0, stream>>>(agg, selfPerm, perm, WSw + 2048, bl_med, hBb, N, 3);
    // Layer 3: hBb -> hAb
    gather_kernel<<<gather_blocks, 256, 0, stream>>>(hBb, rowStartPerm, csrSrc, perm, agg, selfPerm, N);
    matvec_kernel<<<mv_blocks, 256, 0, stream>>>(agg, selfPerm, perm, WSw + 2048, bl_med, hAb, N, 3);
    // Layer 4: hAb -> d_out (no tanh, fp32 out)
    gather_kernel<<<gather_blocks, 256, 0, stream>>>(hAb, rowStartPerm, csrSrc, perm, agg, selfPerm, N);
    matvec_kernel<<<mv_blocks, 256, 0, stream>>>(agg, selfPerm, perm, WSw + 4096, bl_out, d_out, N, 0);
}

// Round 6
// 495.033 us; speedup vs baseline: 1.2021x; 1.2021x over previous
//
#include <hip/hip_runtime.h>
#include <cstdint>

#define F 64
#define NPB 128        // nodes per matvec block / fine-bucket width
#define TILE1 8192     // edges per phase-1a block
#define MAXCB 64       // max coarse buckets (supports N <= 131072)
#define SCAN_BLK 1024

// ---------------------------------------------------------------------------
// bf16 helpers
// ---------------------------------------------------------------------------
__device__ __forceinline__ unsigned short f2b(float f) {     // RNE round
    unsigned u = __float_as_uint(f);
    unsigned r = u + 0x7fffu + ((u >> 16) & 1u);
    return (unsigned short)(r >> 16);
}
__device__ __forceinline__ float4 b2f4(uint2 u) {
    return make_float4(__uint_as_float(u.x << 16),
                       __uint_as_float(u.x & 0xffff0000u),
                       __uint_as_float(u.y << 16),
                       __uint_as_float(u.y & 0xffff0000u));
}
__device__ __forceinline__ void add8(float* a, uint4 u) {
    const unsigned* p = (const unsigned*)&u;
#pragma unroll
    for (int i = 0; i < 4; ++i) {
        a[2 * i + 0] += __uint_as_float(p[i] << 16);
        a[2 * i + 1] += __uint_as_float(p[i] & 0xffff0000u);
    }
}

// ---------------------------------------------------------------------------
// Phase 1a: per-tile histogram by coarse bucket (dst >> 11)
// ---------------------------------------------------------------------------
__global__ __launch_bounds__(256) void hist1a_kernel(
    const int* __restrict__ dst, int* __restrict__ binMat,
    int E, int NB1, int ncb) {
    __shared__ int h[MAXCB];
    int t = threadIdx.x;
    if (t < MAXCB) h[t] = 0;
    __syncthreads();
    int base = blockIdx.x * TILE1;
    int end = min(base + TILE1, E);
    const int4* d4 = (const int4*)dst;
    int n4 = (end - base) >> 2;
    int b4 = base >> 2;
    for (int k = t; k < n4; k += 256) {
        int4 v = d4[b4 + k];
        atomicAdd(&h[v.x >> 11], 1);
        atomicAdd(&h[v.y >> 11], 1);
        atomicAdd(&h[v.z >> 11], 1);
        atomicAdd(&h[v.w >> 11], 1);
    }
    __syncthreads();
    if (t < ncb) binMat[t * NB1 + blockIdx.x] = h[t];
}

// Generic single-block exclusive scan, len <= SCAN_BLK*8
__global__ __launch_bounds__(SCAN_BLK) void scan_kernel(
    int* __restrict__ a, int len) {
    __shared__ int sh[SCAN_BLK];
    int t = threadIdx.x;
    int ch = (len + SCAN_BLK - 1) / SCAN_BLK;
    int b0 = t * ch;
    int loc[8];
    int lsum = 0;
    for (int k = 0; k < ch; ++k) {
        int i = b0 + k;
        int v = (i < len) ? a[i] : 0;
        loc[k] = lsum;
        lsum += v;
    }
    sh[t] = lsum;
    __syncthreads();
    for (int off = 1; off < SCAN_BLK; off <<= 1) {
        int add = (t >= off) ? sh[t - off] : 0;
        __syncthreads();
        sh[t] += add;
        __syncthreads();
    }
    int tex = sh[t] - lsum;
    for (int k = 0; k < ch; ++k) {
        int i = b0 + k;
        if (i < len) a[i] = tex + loc[k];
    }
}

// ---------------------------------------------------------------------------
// Phase 1a scatter: deterministic placement via binMat prefix.
// Packed word: (dst & 2047) << 17 | src   (needs N <= 131072)
// ---------------------------------------------------------------------------
__global__ __launch_bounds__(256) void scatter1a_kernel(
    const int* __restrict__ src, const int* __restrict__ dst,
    const int* __restrict__ binMat, unsigned* __restrict__ stage1,
    int E, int NB1, int ncb) {
    __shared__ int cur[MAXCB];
    int t = threadIdx.x;
    if (t < ncb) cur[t] = binMat[t * NB1 + blockIdx.x];
    __syncthreads();
    int base = blockIdx.x * TILE1;
    int end = min(base + TILE1, E);
    const int4* s4 = (const int4*)src;
    const int4* d4 = (const int4*)dst;
    int n4 = (end - base) >> 2;
    int b4 = base >> 2;
    for (int k = t; k < n4; k += 256) {
        int4 s = s4[b4 + k];
        int4 d = d4[b4 + k];
        int p0 = atomicAdd(&cur[d.x >> 11], 1);
        int p1 = atomicAdd(&cur[d.y >> 11], 1);
        int p2 = atomicAdd(&cur[d.z >> 11], 1);
        int p3 = atomicAdd(&cur[d.w >> 11], 1);
        stage1[p0] = ((unsigned)(d.x & 2047) << 17) | (unsigned)s.x;
        stage1[p1] = ((unsigned)(d.y & 2047) << 17) | (unsigned)s.y;
        stage1[p2] = ((unsigned)(d.z & 2047) << 17) | (unsigned)s.z;
        stage1[p3] = ((unsigned)(d.w & 2047) << 17) | (unsigned)s.w;
    }
}

// ---------------------------------------------------------------------------
// Phase 1b: one block per coarse bucket; split into 16 fine buckets (128
// nodes each) with LDS cursors; emit fineStart.
// ---------------------------------------------------------------------------
__global__ __launch_bounds__(256) void phase1b_kernel(
    const unsigned* __restrict__ stage1, const int* __restrict__ binMat,
    unsigned* __restrict__ stage2, int* __restrict__ fineStart,
    int E, int NB1, int ncb) {
    __shared__ int cnt[16];
    __shared__ int pre[17];
    __shared__ int cur[16];
    int cb = blockIdx.x;
    int t = threadIdx.x;
    int s = binMat[cb * NB1];
    int e2 = (cb + 1 < ncb) ? binMat[(cb + 1) * NB1] : E;
    if (t < 16) cnt[t] = 0;
    __syncthreads();
    for (int i = s + t; i < e2; i += 256)
        atomicAdd(&cnt[(stage1[i] >> 24) & 15], 1);
    __syncthreads();
    if (t == 0) {
        int r = 0;
        for (int j = 0; j < 16; ++j) { pre[j] = r; r += cnt[j]; }
        pre[16] = r;
    }
    __syncthreads();
    if (t < 16) { cur[t] = pre[t]; fineStart[cb * 16 + t] = s + pre[t]; }
    if (t == 0 && cb == ncb - 1) fineStart[ncb * 16] = E;
    __syncthreads();
    for (int i = s + t; i < e2; i += 256) {
        unsigned w = stage1[i];
        int pos = atomicAdd(&cur[(w >> 24) & 15], 1);
        stage2[s + pos] = w;
    }
}

// ---------------------------------------------------------------------------
// Phase 2: one block per fine bucket (128 nodes). Emits csrSrc grouped by
// node AND rowStart (per-node CSR offsets) — replaces count+scan+fill.
// ---------------------------------------------------------------------------
__global__ __launch_bounds__(256) void phase2_kernel(
    const unsigned* __restrict__ stage2, const int* __restrict__ fineStart,
    int* __restrict__ csrSrc, int* __restrict__ rowStart) {
    __shared__ int cnt[128];
    __shared__ int pre[129];
    __shared__ int cur[128];
    int b = blockIdx.x;
    int t = threadIdx.x;
    int s = fineStart[b];
    int e2 = fineStart[b + 1];
    if (t < 128) cnt[t] = 0;
    __syncthreads();
    for (int i = s + t; i < e2; i += 256)
        atomicAdd(&cnt[(stage2[i] >> 17) & 127], 1);
    __syncthreads();
    // parallel exclusive scan of cnt[128] -> pre
    if (t < 128) pre[t + 1] = cnt[t];
    if (t == 0) pre[0] = 0;
    __syncthreads();
    for (int off = 1; off < 128; off <<= 1) {
        int v = 0;
        if (t < 128 && (t + 1) > off) v = pre[t + 1 - off];
        __syncthreads();
        if (t < 128 && (t + 1) > off) pre[t + 1] += v;
        __syncthreads();
    }
    if (t < 128) cur[t] = pre[t];
    if (t < 129) rowStart[b * 128 + t] = s + pre[t];
    __syncthreads();
    for (int i = s + t; i < e2; i += 256) {
        unsigned w = stage2[i];
        int pos = atomicAdd(&cur[(w >> 17) & 127], 1);
        csrSrc[s + pos] = (int)(w & 0x1FFFFu);
    }
}

// ---------------------------------------------------------------------------
// Prep: weight swizzle (blocks 0..23) + x -> bf16 (remaining blocks).
//   WSw[set][m*1024 + f4*64 + k*16 + oc] = W_m[4*oc + k][4*f4 .. 4*f4+3]
// ---------------------------------------------------------------------------
__global__ __launch_bounds__(256) void prep_kernel(
    const float* __restrict__ Wl0, const float* __restrict__ Wr0,
    const float* __restrict__ Wl1, const float* __restrict__ Wr1,
    const float* __restrict__ Wl2, const float* __restrict__ Wr2,
    float4* __restrict__ WSw,
    const float* __restrict__ x, ushort* __restrict__ xb, int nElem) {
    int b = blockIdx.x;
    int t = threadIdx.x;
    if (b < 24) {
        int g = b * 256 + t;
        if (g >= 3 * 2048) return;
        int set = g >> 11;
        int r = g & 2047;
        int m = r >> 10;
        int q = r & 1023;
        int f4 = q >> 6;
        int kk = (q >> 4) & 3;
        int oc = q & 15;
        const float* W = (set == 0) ? (m ? Wr0 : Wl0)
                       : (set == 1) ? (m ? Wr1 : Wl1)
                                    : (m ? Wr2 : Wl2);
        const float4* W4 = (const float4*)W;
        WSw[g] = W4[(4 * oc + kk) * (F / 4) + f4];
    } else {
        int i = (b - 24) * 256 + t;
        int n4 = nElem >> 2;
        if (i < n4) {
            float4 v = ((const float4*)x)[i];
            uint2 o;
            o.x = (unsigned)f2b(v.x) | ((unsigned)f2b(v.y) << 16);
            o.y = (unsigned)f2b(v.z) | ((unsigned)f2b(v.w) << 16);
            ((uint2*)xb)[i] = o;
        }
    }
}

// ---------------------------------------------------------------------------
// Gather: agg[node] = sum_{j in N(node)} hb[j]  (bf16 in, fp32 out)
// Natural node order; 8 lanes/node, 16B per lane, unroll-4 ILP, no LDS.
// ---------------------------------------------------------------------------
__global__ __launch_bounds__(256, 8) void gather_kernel(
    const ushort* __restrict__ hb, const int* __restrict__ rowStart,
    const int* __restrict__ csrSrc, float* __restrict__ agg, int n) {
    int gid = blockIdx.x * 256 + threadIdx.x;
    int node = gid >> 3;
    int c = gid & 7;
    if (node >= n) return;

    const uint4* h16 = (const uint4*)hb;
    float a[8] = {0.f, 0.f, 0.f, 0.f, 0.f, 0.f, 0.f, 0.f};

    int e = rowStart[node];
    int end = rowStart[node + 1];
    for (; e + 3 < end; e += 4) {
        int s0 = csrSrc[e + 0];
        int s1 = csrSrc[e + 1];
        int s2 = csrSrc[e + 2];
        int s3 = csrSrc[e + 3];
        uint4 u0 = h16[(size_t)s0 * 8 + c];
        uint4 u1 = h16[(size_t)s1 * 8 + c];
        uint4 u2 = h16[(size_t)s2 * 8 + c];
        uint4 u3 = h16[(size_t)s3 * 8 + c];
        add8(a, u0); add8(a, u1); add8(a, u2); add8(a, u3);
    }
    for (; e < end; ++e) {
        uint4 u0 = h16[(size_t)csrSrc[e] * 8 + c];
        add8(a, u0);
    }

    float4* o = (float4*)(agg + (size_t)node * F);
    o[2 * c + 0] = make_float4(a[0], a[1], a[2], a[3]);
    o[2 * c + 1] = make_float4(a[4], a[5], a[6], a[7]);
}

// ---------------------------------------------------------------------------
// Matvec: out[n] = act( agg[n] @ Wl^T + bl + hb[n] @ Wr^T )
// NPB=128 nodes/block; LDS weights 32 KB + agg 32 KB; 8 nodes x 4 outs/lane.
// flags: bit0 = tanh, bit1 = bf16 output.
// ---------------------------------------------------------------------------
__global__ __launch_bounds__(256, 2) void matvec_kernel(
    const float* __restrict__ agg, const ushort* __restrict__ hb,
    const float4* __restrict__ WSwSet, const float* __restrict__ bl,
    void* __restrict__ out, int n, int flags) {
    __shared__ float4 WT[2048];
    __shared__ float4 aggT[NPB * 16];

    int t = threadIdx.x;
    int node0 = blockIdx.x * NPB;

#pragma unroll
    for (int i = 0; i < 8; ++i) WT[t + 256 * i] = WSwSet[t + 256 * i];

    const float4* aggG = (const float4*)agg + (size_t)node0 * 16;
#pragma unroll
    for (int k = 0; k < 8; ++k) {
        int idx = k * 256 + t;
        int nn = idx >> 4;
        int f4 = idx & 15;
        aggT[nn * 16 + (f4 ^ ((nn >> 3) & 15))] = aggG[idx];
    }
    __syncthreads();

    int w = t >> 6;
    int lane = t & 63;
    int ng = lane >> 4;
    int oc = lane & 15;
    int nbase = w * 32 + ng * 8;
    int sw = (nbase >> 3) & 15;

    float4 b4 = ((const float4*)bl)[oc];
    float4 acc[8];
#pragma unroll
    for (int j = 0; j < 8; ++j) acc[j] = b4;

    // agg @ Wl
#pragma unroll 4
    for (int f4 = 0; f4 < 16; ++f4) {
        float4 w0 = WT[f4 * 64 + oc];
        float4 w1 = WT[f4 * 64 + 16 + oc];
        float4 w2 = WT[f4 * 64 + 32 + oc];
        float4 w3 = WT[f4 * 64 + 48 + oc];
        int slot = f4 ^ sw;
#pragma unroll
        for (int j = 0; j < 8; ++j) {
            float4 a = aggT[(nbase + j) * 16 + slot];
            acc[j].x += a.x * w0.x + a.y * w0.y + a.z * w0.z + a.w * w0.w;
            acc[j].y += a.x * w1.x + a.y * w1.y + a.z * w1.z + a.w * w1.w;
            acc[j].z += a.x * w2.x + a.y * w2.y + a.z * w2.z + a.w * w2.w;
            acc[j].w += a.x * w3.x + a.y * w3.y + a.z * w3.z + a.w * w3.w;
        }
    }

    // self @ Wr from global bf16 (block tile L1-resident, coalesced)
    const uint2* hb2 = (const uint2*)hb + (size_t)node0 * 16;
#pragma unroll 4
    for (int f4 = 0; f4 < 16; ++f4) {
        float4 w0 = WT[1024 + f4 * 64 + oc];
        float4 w1 = WT[1024 + f4 * 64 + 16 + oc];
        float4 w2 = WT[1024 + f4 * 64 + 32 + oc];
        float4 w3 = WT[1024 + f4 * 64 + 48 + oc];
#pragma unroll
        for (int j = 0; j < 8; ++j) {
            float4 a = b2f4(hb2[(nbase + j) * 16 + f4]);
            acc[j].x += a.x * w0.x + a.y * w0.y + a.z * w0.z + a.w * w0.w;
            acc[j].y += a.x * w1.x + a.y * w1.y + a.z * w1.z + a.w * w1.w;
            acc[j].z += a.x * w2.x + a.y * w2.y + a.z * w2.z + a.w * w2.w;
            acc[j].w += a.x * w3.x + a.y * w3.y + a.z * w3.z + a.w * w3.w;
        }
    }

#pragma unroll
    for (int j = 0; j < 8; ++j) {
        int node = node0 + nbase + j;
        if (node < n) {
            float4 v = acc[j];
            if (flags & 1) {
                v.x = tanhf(v.x); v.y = tanhf(v.y);
                v.z = tanhf(v.z); v.w = tanhf(v.w);
            }
            if (flags & 2) {
                uint2 o;
                o.x = (unsigned)f2b(v.x) | ((unsigned)f2b(v.y) << 16);
                o.y = (unsigned)f2b(v.z) | ((unsigned)f2b(v.w) << 16);
                ((uint2*)out)[(size_t)node * 16 + oc] = o;
            } else {
                ((float4*)out)[(size_t)node * 16 + oc] = v;
            }
        }
    }
}

// ---------------------------------------------------------------------------
// Launch
// ---------------------------------------------------------------------------
extern "C" void kernel_launch(void* const* d_in, const int* in_sizes, int n_in,
                              void* d_out, int out_size, void* d_ws, size_t ws_size,
                              hipStream_t stream) {
    const float* x      = (const float*)d_in[0];
    const int*   edges  = (const int*)d_in[1];
    const float* Wl_in  = (const float*)d_in[2];
    const float* bl_in  = (const float*)d_in[3];
    const float* Wr_in  = (const float*)d_in[4];
    const float* Wl_med = (const float*)d_in[5];
    const float* bl_med = (const float*)d_in[6];
    const float* Wr_med = (const float*)d_in[7];
    const float* Wl_out = (const float*)d_in[8];
    const float* bl_out = (const float*)d_in[9];
    const float* Wr_out = (const float*)d_in[10];

    const int N = in_sizes[0] / F;
    const int E = in_sizes[1] / 2;
    const int* src = edges;
    const int* dst = edges + E;

    const int ncb = (N + 2047) >> 11;            // coarse buckets (49)
    const int NB1 = (E + TILE1 - 1) / TILE1;     // phase-1a tiles (147)
    const int nfineT = ncb * 16;                 // fine buckets (784)
    const int NR = nfineT * 128;                 // padded node count (100352)

    // Workspace layout
    float4*  WSw       = (float4*)d_ws;                        // 6144
    float*   agg       = (float*)(WSw + 6144);                 // NR*F fp32
    ushort*  xb        = (ushort*)(agg + (size_t)NR * F);      // N*F bf16
    ushort*  hAb       = xb + (size_t)N * F;                   // N*F bf16
    ushort*  hBb       = hAb + (size_t)N * F;                  // N*F bf16
    int*     rowStart  = (int*)(hBb + (size_t)N * F);          // NR+2
    int*     fineStart = rowStart + NR + 2;                    // nfineT+1
    int*     binMat    = fineStart + nfineT + 1;               // ncb*NB1
    unsigned* stage1   = (unsigned*)(binMat + ncb * NB1);      // E
    unsigned* stage2   = stage1 + E;                           // E
    int*     csrSrc    = (int*)(stage2 + E);                   // E

    const int gather_blocks = (N * 8 + 255) / 256;
    const int prep_blocks = 24 + (N * F / 4 + 255) / 256;

    // Prep (weights + x->bf16)
    prep_kernel<<<prep_blocks, 256, 0, stream>>>(Wl_in, Wr_in, Wl_med, Wr_med,
                                                 Wl_out, Wr_out, WSw, x, xb, N * F);

    // Edge bucketing pipeline -> csrSrc + rowStart (no global atomote memsets)
    hist1a_kernel<<<NB1, 256, 0, stream>>>(dst, binMat, E, NB1, ncb);
    scan_kernel<<<1, SCAN_BLK, 0, stream>>>(binMat, ncb * NB1);
    scatter1a_kernel<<<NB1, 256, 0, stream>>>(src, dst, binMat, stage1, E, NB1, ncb);
    phase1b_kernel<<<ncb, 256, 0, stream>>>(stage1, binMat, stage2, fineStart, E, NB1, ncb);
    phase2_kernel<<<nfineT, 256, 0, stream>>>(stage2, fineStart, csrSrc, rowStart);

    // Layer 1: xb -> hAb (tanh, bf16 out)
    gather_kernel<<<gather_blocks, 256, 0, stream>>>(xb, rowStart, csrSrc, agg, N);
    matvec_kernel<<<nfineT, 256, 0, stream>>>(agg, xb, WSw + 0, bl_in, hAb, N, 3);
    // Layer 2: hAb -> hBb
    gather_kernel<<<gather_blocks, 256, 0, stream>>>(hAb, rowStart, csrSrc, agg, N);
    matvec_kernel<<<nfineT, 256, 0, stream>>>(agg, hAb, WSw + 2048, bl_med, hBb, N, 3);
    // Layer 3: hBb -> hAb
    gather_kernel<<<gather_blocks, 256, 0, stream>>>(hBb, rowStart, csrSrc, agg, N);
    matvec_kernel<<<nfineT, 256, 0, stream>>>(agg, hBb, WSw + 2048, bl_med, hAb, N, 3);
    // Layer 4: hAb -> d_out (no tanh, fp32 out)
    gather_kernel<<<gather_blocks, 256, 0, stream>>>(hAb, rowStart, csrSrc, agg, N);
    matvec_kernel<<<nfineT, 256, 0, stream>>>(agg, hAb, WSw + 4096, bl_out, d_out, N, 0);
}

// Round 7
// 332.619 us; speedup vs baseline: 1.7891x; 1.4883x over previous
//
#include <hip/hip_runtime.h>
#include <cstdint>

#define F 64
#define TILE1 8192     // edges per phase-1a block
#define MAXCB 64       // max coarse buckets (supports N <= 131072)
#define SCAN_BLK 1024

typedef short bf16x8 __attribute__((ext_vector_type(8)));
typedef float f32x4  __attribute__((ext_vector_type(4)));

// ---------------------------------------------------------------------------
// bf16 helpers
// ---------------------------------------------------------------------------
__device__ __forceinline__ unsigned short f2b(float f) {     // RNE round
    unsigned u = __float_as_uint(f);
    unsigned r = u + 0x7fffu + ((u >> 16) & 1u);
    return (unsigned short)(r >> 16);
}
__device__ __forceinline__ void add8(float* a, uint4 u) {
    const unsigned* p = (const unsigned*)&u;
#pragma unroll
    for (int i = 0; i < 4; ++i) {
        a[2 * i + 0] += __uint_as_float(p[i] << 16);
        a[2 * i + 1] += __uint_as_float(p[i] & 0xffff0000u);
    }
}

// ---------------------------------------------------------------------------
// Phase 1a: per-tile histogram by coarse bucket (dst >> 11)
// ---------------------------------------------------------------------------
__global__ __launch_bounds__(256) void hist1a_kernel(
    const int* __restrict__ dst, int* __restrict__ binMat,
    int E, int NB1, int ncb) {
    __shared__ int h[MAXCB];
    int t = threadIdx.x;
    if (t < MAXCB) h[t] = 0;
    __syncthreads();
    int base = blockIdx.x * TILE1;
    int end = min(base + TILE1, E);
    const int4* d4 = (const int4*)dst;
    int n4 = (end - base) >> 2;
    int b4 = base >> 2;
    for (int k = t; k < n4; k += 256) {
        int4 v = d4[b4 + k];
        atomicAdd(&h[v.x >> 11], 1);
        atomicAdd(&h[v.y >> 11], 1);
        atomicAdd(&h[v.z >> 11], 1);
        atomicAdd(&h[v.w >> 11], 1);
    }
    __syncthreads();
    if (t < ncb) binMat[t * NB1 + blockIdx.x] = h[t];
}

// Generic single-block exclusive scan, len <= SCAN_BLK*8
__global__ __launch_bounds__(SCAN_BLK) void scan_kernel(
    int* __restrict__ a, int len) {
    __shared__ int sh[SCAN_BLK];
    int t = threadIdx.x;
    int ch = (len + SCAN_BLK - 1) / SCAN_BLK;
    int b0 = t * ch;
    int loc[8];
    int lsum = 0;
    for (int k = 0; k < ch; ++k) {
        int i = b0 + k;
        int v = (i < len) ? a[i] : 0;
        loc[k] = lsum;
        lsum += v;
    }
    sh[t] = lsum;
    __syncthreads();
    for (int off = 1; off < SCAN_BLK; off <<= 1) {
        int add = (t >= off) ? sh[t - off] : 0;
        __syncthreads();
        sh[t] += add;
        __syncthreads();
    }
    int tex = sh[t] - lsum;
    for (int k = 0; k < ch; ++k) {
        int i = b0 + k;
        if (i < len) a[i] = tex + loc[k];
    }
}

// ---------------------------------------------------------------------------
// Phase 1a scatter: deterministic placement via binMat prefix.
// Packed word: (dst & 2047) << 17 | src   (needs N <= 131072)
// ---------------------------------------------------------------------------
__global__ __launch_bounds__(256) void scatter1a_kernel(
    const int* __restrict__ src, const int* __restrict__ dst,
    const int* __restrict__ binMat, unsigned* __restrict__ stage1,
    int E, int NB1, int ncb) {
    __shared__ int cur[MAXCB];
    int t = threadIdx.x;
    if (t < ncb) cur[t] = binMat[t * NB1 + blockIdx.x];
    __syncthreads();
    int base = blockIdx.x * TILE1;
    int end = min(base + TILE1, E);
    const int4* s4 = (const int4*)src;
    const int4* d4 = (const int4*)dst;
    int n4 = (end - base) >> 2;
    int b4 = base >> 2;
    for (int k = t; k < n4; k += 256) {
        int4 s = s4[b4 + k];
        int4 d = d4[b4 + k];
        int p0 = atomicAdd(&cur[d.x >> 11], 1);
        int p1 = atomicAdd(&cur[d.y >> 11], 1);
        int p2 = atomicAdd(&cur[d.z >> 11], 1);
        int p3 = atomicAdd(&cur[d.w >> 11], 1);
        stage1[p0] = ((unsigned)(d.x & 2047) << 17) | (unsigned)s.x;
        stage1[p1] = ((unsigned)(d.y & 2047) << 17) | (unsigned)s.y;
        stage1[p2] = ((unsigned)(d.z & 2047) << 17) | (unsigned)s.z;
        stage1[p3] = ((unsigned)(d.w & 2047) << 17) | (unsigned)s.w;
    }
}

// ---------------------------------------------------------------------------
// Phase 1b: one block per coarse bucket; split into 16 fine buckets.
// ---------------------------------------------------------------------------
__global__ __launch_bounds__(256) void phase1b_kernel(
    const unsigned* __restrict__ stage1, const int* __restrict__ binMat,
    unsigned* __restrict__ stage2, int* __restrict__ fineStart,
    int E, int NB1, int ncb) {
    __shared__ int cnt[16];
    __shared__ int pre[17];
    __shared__ int cur[16];
    int cb = blockIdx.x;
    int t = threadIdx.x;
    int s = binMat[cb * NB1];
    int e2 = (cb + 1 < ncb) ? binMat[(cb + 1) * NB1] : E;
    if (t < 16) cnt[t] = 0;
    __syncthreads();
    for (int i = s + t; i < e2; i += 256)
        atomicAdd(&cnt[(stage1[i] >> 24) & 15], 1);
    __syncthreads();
    if (t == 0) {
        int r = 0;
        for (int j = 0; j < 16; ++j) { pre[j] = r; r += cnt[j]; }
        pre[16] = r;
    }
    __syncthreads();
    if (t < 16) { cur[t] = pre[t]; fineStart[cb * 16 + t] = s + pre[t]; }
    if (t == 0 && cb == ncb - 1) fineStart[ncb * 16] = E;
    __syncthreads();
    for (int i = s + t; i < e2; i += 256) {
        unsigned w = stage1[i];
        int pos = atomicAdd(&cur[(w >> 24) & 15], 1);
        stage2[s + pos] = w;
    }
}

// ---------------------------------------------------------------------------
// Phase 2: one block per fine bucket (128 nodes) -> csrSrc + rowStart.
// ---------------------------------------------------------------------------
__global__ __launch_bounds__(256) void phase2_kernel(
    const unsigned* __restrict__ stage2, const int* __restrict__ fineStart,
    int* __restrict__ csrSrc, int* __restrict__ rowStart) {
    __shared__ int cnt[128];
    __shared__ int pre[129];
    __shared__ int cur[128];
    int b = blockIdx.x;
    int t = threadIdx.x;
    int s = fineStart[b];
    int e2 = fineStart[b + 1];
    if (t < 128) cnt[t] = 0;
    __syncthreads();
    for (int i = s + t; i < e2; i += 256)
        atomicAdd(&cnt[(stage2[i] >> 17) & 127], 1);
    __syncthreads();
    if (t < 128) pre[t + 1] = cnt[t];
    if (t == 0) pre[0] = 0;
    __syncthreads();
    for (int off = 1; off < 128; off <<= 1) {
        int v = 0;
        if (t < 128 && (t + 1) > off) v = pre[t + 1 - off];
        __syncthreads();
        if (t < 128 && (t + 1) > off) pre[t + 1] += v;
        __syncthreads();
    }
    if (t < 128) cur[t] = pre[t];
    if (t < 129) rowStart[b * 128 + t] = s + pre[t];
    __syncthreads();
    for (int i = s + t; i < e2; i += 256) {
        unsigned w = stage2[i];
        int pos = atomicAdd(&cur[(w >> 17) & 127], 1);
        csrSrc[s + pos] = (int)(w & 0x1FFFFu);
    }
}

// ---------------------------------------------------------------------------
// Prep: weight B-fragments (blocks 0..11) + x -> bf16 (remaining blocks).
// wbuf frag f = s*4+ot, lane l, j in 0..7:
//   element = B[k][o], k = s*32 + (l>>4)*8 + j, o = ot*16 + (l&15)
//   B[k][o] = (k < 64) ? Wl[o][k] : Wr[o][k-64]
// Stored: wbuf[set][ (f*64 + l)*8 + j ] as bf16. 1024 threads/set.
// ---------------------------------------------------------------------------
__global__ __launch_bounds__(256) void prep_kernel(
    const float* __restrict__ Wl0, const float* __restrict__ Wr0,
    const float* __restrict__ Wl1, const float* __restrict__ Wr1,
    const float* __restrict__ Wl2, const float* __restrict__ Wr2,
    ushort* __restrict__ wbuf,
    const float* __restrict__ x, ushort* __restrict__ xb, int nElem) {
    int b = blockIdx.x;
    int t = threadIdx.x;
    if (b < 12) {
        int g = b * 256 + t;          // g < 3072 = 3 sets * 16 frags * 64 lanes
        int set = g >> 10;
        int fl = g & 1023;
        int f = fl >> 6;              // frag id = s*4+ot
        int l = fl & 63;
        int s = f >> 2;
        int ot = f & 3;
        const float* Wl = (set == 0) ? Wl0 : (set == 1) ? Wl1 : Wl2;
        const float* Wr = (set == 0) ? Wr0 : (set == 1) ? Wr1 : Wr2;
        int o = ot * 16 + (l & 15);
        int k0 = s * 32 + (l >> 4) * 8;
        unsigned d[4];
#pragma unroll
        for (int p = 0; p < 4; ++p) {
            int ka = k0 + 2 * p, kb = k0 + 2 * p + 1;
            float va = (ka < 64) ? Wl[o * 64 + ka] : Wr[o * 64 + (ka - 64)];
            float vb = (kb < 64) ? Wl[o * 64 + kb] : Wr[o * 64 + (kb - 64)];
            d[p] = (unsigned)f2b(va) | ((unsigned)f2b(vb) << 16);
        }
        ((uint4*)wbuf)[g] = make_uint4(d[0], d[1], d[2], d[3]);
    } else {
        int i = (b - 12) * 256 + t;   // float4 index
        int n4 = nElem >> 2;
        if (i < n4) {
            float4 v = ((const float4*)x)[i];
            uint2 o;
            o.x = (unsigned)f2b(v.x) | ((unsigned)f2b(v.y) << 16);
            o.y = (unsigned)f2b(v.z) | ((unsigned)f2b(v.w) << 16);
            ((uint2*)xb)[i] = o;
        }
    }
}

// ---------------------------------------------------------------------------
// Gather: aggB[node] = sum_{j in N(node)} hb[j]  (bf16 in, bf16 out, fp32 acc)
// 8 lanes/node, 16B per lane, unroll-4 ILP, no LDS. Covers padded NR nodes
// (pad rows have empty CSR -> zeros).
// ---------------------------------------------------------------------------
__global__ __launch_bounds__(256, 8) void gather_kernel(
    const ushort* __restrict__ hb, const int* __restrict__ rowStart,
    const int* __restrict__ csrSrc, ushort* __restrict__ aggB, int nr) {
    int gid = blockIdx.x * 256 + threadIdx.x;
    int node = gid >> 3;
    int c = gid & 7;
    if (node >= nr) return;

    const uint4* h16 = (const uint4*)hb;
    float a[8] = {0.f, 0.f, 0.f, 0.f, 0.f, 0.f, 0.f, 0.f};

    int e = rowStart[node];
    int end = rowStart[node + 1];
    for (; e + 3 < end; e += 4) {
        int s0 = csrSrc[e + 0];
        int s1 = csrSrc[e + 1];
        int s2 = csrSrc[e + 2];
        int s3 = csrSrc[e + 3];
        uint4 u0 = h16[(size_t)s0 * 8 + c];
        uint4 u1 = h16[(size_t)s1 * 8 + c];
        uint4 u2 = h16[(size_t)s2 * 8 + c];
        uint4 u3 = h16[(size_t)s3 * 8 + c];
        add8(a, u0); add8(a, u1); add8(a, u2); add8(a, u3);
    }
    for (; e < end; ++e) {
        uint4 u0 = h16[(size_t)csrSrc[e] * 8 + c];
        add8(a, u0);
    }

    unsigned d[4];
#pragma unroll
    for (int p = 0; p < 4; ++p)
        d[p] = (unsigned)f2b(a[2 * p]) | ((unsigned)f2b(a[2 * p + 1]) << 16);
    ((uint4*)aggB)[(size_t)node * 8 + c] = make_uint4(d[0], d[1], d[2], d[3]);
}

// ---------------------------------------------------------------------------
// MFMA matvec: out[n] = act( [aggB | self] @ [Wl;Wr]^T + bl )
// 128 nodes/block, 4 waves x 32 nodes (2 m-tiles). K=128 in 4 steps of 32:
// s=0,1 read aggB, s=2,3 read hb. A: lane holds A[m=l&15][k=quad*8+j].
// B frags preswizzled in wbuf. C: col=l&15, row=quad*4+reg.
// Epilogue transposes C through LDS (stride 68 dwords, wave-private rows).
// flags: bit0 = tanh, bit1 = bf16 output.
// ---------------------------------------------------------------------------
__global__ __launch_bounds__(256, 4) void matvec_mfma(
    const ushort* __restrict__ aggB, const ushort* __restrict__ hb,
    const ushort* __restrict__ wbuf, const float* __restrict__ bl,
    void* __restrict__ out, int n, int flags) {
    __shared__ float outT[128 * 68];   // 34 KB

    int t = threadIdx.x;
    int w = t >> 6;
    int l = t & 63;
    int quad = l >> 4;
    int lo = l & 15;
    int node0 = blockIdx.x * 128 + w * 32;

    f32x4 acc[2][4];
#pragma unroll
    for (int ot = 0; ot < 4; ++ot) {
        float bv = bl[ot * 16 + lo];
        f32x4 bvv = {bv, bv, bv, bv};
        acc[0][ot] = bvv;
        acc[1][ot] = bvv;
    }

#pragma unroll
    for (int s = 0; s < 4; ++s) {
        const ushort* hbase = (s < 2) ? aggB : hb;
        bf16x8 A[2];
#pragma unroll
        for (int mt = 0; mt < 2; ++mt) {
            size_t node = (size_t)node0 + mt * 16 + lo;
            A[mt] = *(const bf16x8*)(hbase + node * 64 + (s & 1) * 32 + quad * 8);
        }
#pragma unroll
        for (int ot = 0; ot < 4; ++ot) {
            bf16x8 B = *(const bf16x8*)(wbuf + (((s * 4 + ot) * 64) + l) * 8);
#pragma unroll
            for (int mt = 0; mt < 2; ++mt)
                acc[mt][ot] = __builtin_amdgcn_mfma_f32_16x16x32_bf16(
                    A[mt], B, acc[mt][ot], 0, 0, 0);
        }
    }

    // Epilogue: tanh + transpose via LDS (wave-private rows, no barrier)
#pragma unroll
    for (int mt = 0; mt < 2; ++mt) {
#pragma unroll
        for (int ot = 0; ot < 4; ++ot) {
            f32x4 v = acc[mt][ot];
            if (flags & 1) {
                v[0] = tanhf(v[0]); v[1] = tanhf(v[1]);
                v[2] = tanhf(v[2]); v[3] = tanhf(v[3]);
            }
            int row = w * 32 + mt * 16 + quad * 4;
            int col = ot * 16 + lo;
#pragma unroll
            for (int r = 0; r < 4; ++r)
                outT[(row + r) * 68 + col] = v[r];
        }
    }

    int row = w * 32 + (l >> 1);
    int node = blockIdx.x * 128 + row;
    int colb = (l & 1) * 32;            // fp32 column base
    if (node < n) {
        const float* srcp = &outT[row * 68 + colb];
        if (flags & 2) {
            uint4* o8 = (uint4*)out;    // bf16 row = 8 uint4
#pragma unroll
            for (int q = 0; q < 4; ++q) {
                unsigned d[4];
#pragma unroll
                for (int p = 0; p < 4; ++p) {
                    float va = srcp[q * 8 + 2 * p];
                    float vb = srcp[q * 8 + 2 * p + 1];
                    d[p] = (unsigned)f2b(va) | ((unsigned)f2b(vb) << 16);
                }
                o8[(size_t)node * 8 + (l & 1) * 4 + q] = make_uint4(d[0], d[1], d[2], d[3]);
            }
        } else {
            float4* o16 = (float4*)out; // fp32 row = 16 float4
#pragma unroll
            for (int q = 0; q < 8; ++q) {
                float4 v = *(const float4*)(srcp + q * 4);
                o16[(size_t)node * 16 + (l & 1) * 8 + q] = v;
            }
        }
    }
}

// ---------------------------------------------------------------------------
// Launch
// ---------------------------------------------------------------------------
extern "C" void kernel_launch(void* const* d_in, const int* in_sizes, int n_in,
                              void* d_out, int out_size, void* d_ws, size_t ws_size,
                              hipStream_t stream) {
    const float* x      = (const float*)d_in[0];
    const int*   edges  = (const int*)d_in[1];
    const float* Wl_in  = (const float*)d_in[2];
    const float* bl_in  = (const float*)d_in[3];
    const float* Wr_in  = (const float*)d_in[4];
    const float* Wl_med = (const float*)d_in[5];
    const float* bl_med = (const float*)d_in[6];
    const float* Wr_med = (const float*)d_in[7];
    const float* Wl_out = (const float*)d_in[8];
    const float* bl_out = (const float*)d_in[9];
    const float* Wr_out = (const float*)d_in[10];

    const int N = in_sizes[0] / F;
    const int E = in_sizes[1] / 2;
    const int* src = edges;
    const int* dst = edges + E;

    const int ncb = (N + 2047) >> 11;            // coarse buckets
    const int NB1 = (E + TILE1 - 1) / TILE1;     // phase-1a tiles
    const int nfineT = ncb * 16;                 // fine buckets
    const int NR = nfineT * 128;                 // padded node count

    // Workspace layout (16B-aligned chunks)
    ushort*  wbuf      = (ushort*)d_ws;                        // 3*8192 bf16
    ushort*  aggB      = wbuf + 3 * 8192;                      // NR*F bf16
    ushort*  xb        = aggB + (size_t)NR * F;                // NR*F bf16
    ushort*  hAb       = xb + (size_t)NR * F;                  // NR*F bf16
    ushort*  hBb       = hAb + (size_t)NR * F;                 // NR*F bf16
    int*     rowStart  = (int*)(hBb + (size_t)NR * F);         // NR+2
    int*     fineStart = rowStart + NR + 2;                    // nfineT+1
    int*     binMat    = fineStart + nfineT + 1;               // ncb*NB1
    unsigned* stage1   = (unsigned*)(binMat + ncb * NB1);      // E
    unsigned* stage2   = stage1 + E;                           // E
    int*     csrSrc    = (int*)(stage2 + E);                   // E

    const int gather_blocks = NR / 32;          // NR*8/256
    const int prep_blocks = 12 + (N * F / 4 + 255) / 256;

    // Prep (weight B-frags + x->bf16)
    prep_kernel<<<prep_blocks, 256, 0, stream>>>(Wl_in, Wr_in, Wl_med, Wr_med,
                                                 Wl_out, Wr_out, wbuf, x, xb, N * F);

    // Edge bucketing pipeline -> csrSrc + rowStart
    hist1a_kernel<<<NB1, 256, 0, stream>>>(dst, binMat, E, NB1, ncb);
    scan_kernel<<<1, SCAN_BLK, 0, stream>>>(binMat, ncb * NB1);
    scatter1a_kernel<<<NB1, 256, 0, stream>>>(src, dst, binMat, stage1, E, NB1, ncb);
    phase1b_kernel<<<ncb, 256, 0, stream>>>(stage1, binMat, stage2, fineStart, E, NB1, ncb);
    phase2_kernel<<<nfineT, 256, 0, stream>>>(stage2, fineStart, csrSrc, rowStart);

    // Layer 1: xb -> hAb (tanh, bf16 out)
    gather_kernel<<<gather_blocks, 256, 0, stream>>>(xb, rowStart, csrSrc, aggB, NR);
    matvec_mfma<<<nfineT, 256, 0, stream>>>(aggB, xb, wbuf + 0,     bl_in,  hAb,   N, 3);
    // Layer 2: hAb -> hBb
    gather_kernel<<<gather_blocks, 256, 0, stream>>>(hAb, rowStart, csrSrc, aggB, NR);
    matvec_mfma<<<nfineT, 256, 0, stream>>>(aggB, hAb, wbuf + 8192, bl_med, hBb,   N, 3);
    // Layer 3: hBb -> hAb
    gather_kernel<<<gather_blocks, 256, 0, stream>>>(hBb, rowStart, csrSrc, aggB, NR);
    matvec_mfma<<<nfineT, 256, 0, stream>>>(aggB, hBb, wbuf + 8192, bl_med, hAb,   N, 3);
    // Layer 4: hAb -> d_out (no tanh, fp32 out)
    gather_kernel<<<gather_blocks, 256, 0, stream>>>(hAb, rowStart, csrSrc, aggB, NR);
    matvec_mfma<<<nfineT, 256, 0, stream>>>(aggB, hAb, wbuf + 16384, bl_out, d_out, N, 0);
}

// Round 8
// 301.520 us; speedup vs baseline: 1.9737x; 1.1031x over previous
//
#include <hip/hip_runtime.h>
#include <cstdint>

#define F 64
#define TILE1 8192     // edges per bucketing tile
#define MAXFB 1024     // max fine buckets (supports N <= 131072)
#define SCAN_BLK 1024

typedef short bf16x8 __attribute__((ext_vector_type(8)));
typedef float f32x4  __attribute__((ext_vector_type(4)));

// ---------------------------------------------------------------------------
// bf16 helpers
// ---------------------------------------------------------------------------
__device__ __forceinline__ unsigned short f2b(float f) {     // RNE round
    unsigned u = __float_as_uint(f);
    unsigned r = u + 0x7fffu + ((u >> 16) & 1u);
    return (unsigned short)(r >> 16);
}
__device__ __forceinline__ void add8(float* a, uint4 u) {
    const unsigned* p = (const unsigned*)&u;
#pragma unroll
    for (int i = 0; i < 4; ++i) {
        a[2 * i + 0] += __uint_as_float(p[i] << 16);
        a[2 * i + 1] += __uint_as_float(p[i] & 0xffff0000u);
    }
}

// ---------------------------------------------------------------------------
// Hist: per-tile histogram by fine bucket (dst >> 7), 782 bins in LDS.
// ---------------------------------------------------------------------------
__global__ __launch_bounds__(256) void hist_kernel(
    const int* __restrict__ dst, int* __restrict__ binMat,
    int E, int NB1, int nf) {
    __shared__ int h[MAXFB];
    int t = threadIdx.x;
    for (int i = t; i < nf; i += 256) h[i] = 0;
    __syncthreads();
    int base = blockIdx.x * TILE1;
    int end = min(base + TILE1, E);
    const int4* d4 = (const int4*)dst;
    int n4 = (end - base) >> 2;
    int b4 = base >> 2;
    for (int k = t; k < n4; k += 256) {
        int4 v = d4[b4 + k];
        atomicAdd(&h[v.x >> 7], 1);
        atomicAdd(&h[v.y >> 7], 1);
        atomicAdd(&h[v.z >> 7], 1);
        atomicAdd(&h[v.w >> 7], 1);
    }
    __syncthreads();
    for (int i = t; i < nf; i += 256) binMat[i * NB1 + blockIdx.x] = h[i];
}

// ---------------------------------------------------------------------------
// Multi-block exclusive scan (in-place) of binMat[len]
// ---------------------------------------------------------------------------
__global__ __launch_bounds__(SCAN_BLK) void scan_blocks_kernel(
    int* __restrict__ a, int* __restrict__ blockSums, int len) {
    __shared__ int sh[SCAN_BLK];
    int t = threadIdx.x;
    int i = blockIdx.x * SCAN_BLK + t;
    int v = (i < len) ? a[i] : 0;
    sh[t] = v;
    __syncthreads();
    for (int off = 1; off < SCAN_BLK; off <<= 1) {
        int add = (t >= off) ? sh[t - off] : 0;
        __syncthreads();
        sh[t] += add;
        __syncthreads();
    }
    int incl = sh[t];
    if (i < len) a[i] = incl - v;
    if (t == SCAN_BLK - 1) blockSums[blockIdx.x] = incl;
}

__global__ __launch_bounds__(SCAN_BLK) void scan_sums_kernel(
    int* __restrict__ blockSums, int nb) {
    __shared__ int sh[SCAN_BLK];
    int t = threadIdx.x;
    int v = (t < nb) ? blockSums[t] : 0;
    sh[t] = v;
    __syncthreads();
    for (int off = 1; off < SCAN_BLK; off <<= 1) {
        int add = (t >= off) ? sh[t - off] : 0;
        __syncthreads();
        sh[t] += add;
        __syncthreads();
    }
    if (t < nb) blockSums[t] = sh[t] - v;
}

__global__ __launch_bounds__(256) void scan_add_kernel(
    int* __restrict__ a, const int* __restrict__ blockSums, int len) {
    int i = blockIdx.x * 256 + threadIdx.x;
    if (i < len) a[i] += blockSums[i >> 10];
}

// ---------------------------------------------------------------------------
// Scatter: deterministic placement into fine-bucket-sorted stage2.
// Packed word: (dst & 127) << 17 | src   (needs N <= 131072)
// ---------------------------------------------------------------------------
__global__ __launch_bounds__(256) void scatter_kernel(
    const int* __restrict__ src, const int* __restrict__ dst,
    const int* __restrict__ binMat, unsigned* __restrict__ stage2,
    int E, int NB1, int nf) {
    __shared__ int cur[MAXFB];
    int t = threadIdx.x;
    for (int i = t; i < nf; i += 256) cur[i] = binMat[i * NB1 + blockIdx.x];
    __syncthreads();
    int base = blockIdx.x * TILE1;
    int end = min(base + TILE1, E);
    const int4* s4 = (const int4*)src;
    const int4* d4 = (const int4*)dst;
    int n4 = (end - base) >> 2;
    int b4 = base >> 2;
    for (int k = t; k < n4; k += 256) {
        int4 s = s4[b4 + k];
        int4 d = d4[b4 + k];
        int p0 = atomicAdd(&cur[d.x >> 7], 1);
        int p1 = atomicAdd(&cur[d.y >> 7], 1);
        int p2 = atomicAdd(&cur[d.z >> 7], 1);
        int p3 = atomicAdd(&cur[d.w >> 7], 1);
        stage2[p0] = ((unsigned)(d.x & 127) << 17) | (unsigned)s.x;
        stage2[p1] = ((unsigned)(d.y & 127) << 17) | (unsigned)s.y;
        stage2[p2] = ((unsigned)(d.z & 127) << 17) | (unsigned)s.z;
        stage2[p3] = ((unsigned)(d.w & 127) << 17) | (unsigned)s.w;
    }
}

// ---------------------------------------------------------------------------
// Phase 2: one block per fine bucket (128 nodes) -> csrSrc + rowStart.
// ---------------------------------------------------------------------------
__global__ __launch_bounds__(256) void phase2_kernel(
    const unsigned* __restrict__ stage2, const int* __restrict__ binMat,
    int* __restrict__ csrSrc, int* __restrict__ rowStart,
    int E, int NB1, int nf) {
    __shared__ int cnt[128];
    __shared__ int pre[129];
    __shared__ int cur[128];
    int b = blockIdx.x;
    int t = threadIdx.x;
    int s = binMat[b * NB1];
    int e2 = (b + 1 < nf) ? binMat[(b + 1) * NB1] : E;
    if (t < 128) cnt[t] = 0;
    __syncthreads();
    for (int i = s + t; i < e2; i += 256)
        atomicAdd(&cnt[(stage2[i] >> 17) & 127], 1);
    __syncthreads();
    if (t < 128) pre[t + 1] = cnt[t];
    if (t == 0) pre[0] = 0;
    __syncthreads();
    for (int off = 1; off < 128; off <<= 1) {
        int v = 0;
        if (t < 128 && (t + 1) > off) v = pre[t + 1 - off];
        __syncthreads();
        if (t < 128 && (t + 1) > off) pre[t + 1] += v;
        __syncthreads();
    }
    if (t < 128) cur[t] = pre[t];
    if (t < 129) rowStart[b * 128 + t] = s + pre[t];
    __syncthreads();
    for (int i = s + t; i < e2; i += 256) {
        unsigned w = stage2[i];
        int pos = atomicAdd(&cur[(w >> 17) & 127], 1);
        csrSrc[s + pos] = (int)(w & 0x1FFFFu);
    }
}

// ---------------------------------------------------------------------------
// Prep: weight B-fragments (blocks 0..11) + x -> bf16 (remaining blocks).
// ---------------------------------------------------------------------------
__global__ __launch_bounds__(256) void prep_kernel(
    const float* __restrict__ Wl0, const float* __restrict__ Wr0,
    const float* __restrict__ Wl1, const float* __restrict__ Wr1,
    const float* __restrict__ Wl2, const float* __restrict__ Wr2,
    ushort* __restrict__ wbuf,
    const float* __restrict__ x, ushort* __restrict__ xb, int nElem) {
    int b = blockIdx.x;
    int t = threadIdx.x;
    if (b < 12) {
        int g = b * 256 + t;          // g < 3072 = 3 sets * 16 frags * 64 lanes
        int set = g >> 10;
        int fl = g & 1023;
        int f = fl >> 6;              // frag id = s*4+ot
        int l = fl & 63;
        int s = f >> 2;
        int ot = f & 3;
        const float* Wl = (set == 0) ? Wl0 : (set == 1) ? Wl1 : Wl2;
        const float* Wr = (set == 0) ? Wr0 : (set == 1) ? Wr1 : Wr2;
        int o = ot * 16 + (l & 15);
        int k0 = s * 32 + (l >> 4) * 8;
        unsigned d[4];
#pragma unroll
        for (int p = 0; p < 4; ++p) {
            int ka = k0 + 2 * p, kb = k0 + 2 * p + 1;
            float va = (ka < 64) ? Wl[o * 64 + ka] : Wr[o * 64 + (ka - 64)];
            float vb = (kb < 64) ? Wl[o * 64 + kb] : Wr[o * 64 + (kb - 64)];
            d[p] = (unsigned)f2b(va) | ((unsigned)f2b(vb) << 16);
        }
        ((uint4*)wbuf)[g] = make_uint4(d[0], d[1], d[2], d[3]);
    } else {
        int i = (b - 12) * 256 + t;   // float4 index
        int n4 = nElem >> 2;
        if (i < n4) {
            float4 v = ((const float4*)x)[i];
            uint2 o;
            o.x = (unsigned)f2b(v.x) | ((unsigned)f2b(v.y) << 16);
            o.y = (unsigned)f2b(v.z) | ((unsigned)f2b(v.w) << 16);
            ((uint2*)xb)[i] = o;
        }
    }
}

// ---------------------------------------------------------------------------
// Gather: aggB[node] = sum_{j in N(node)} hb[j]  (bf16 in, bf16 out, fp32 acc)
// 8 lanes/node, 16B per lane, unroll-4 ILP, no LDS. Covers padded NR nodes.
// ---------------------------------------------------------------------------
__global__ __launch_bounds__(256, 8) void gather_kernel(
    const ushort* __restrict__ hb, const int* __restrict__ rowStart,
    const int* __restrict__ csrSrc, ushort* __restrict__ aggB, int nr) {
    int gid = blockIdx.x * 256 + threadIdx.x;
    int node = gid >> 3;
    int c = gid & 7;
    if (node >= nr) return;

    const uint4* h16 = (const uint4*)hb;
    float a[8] = {0.f, 0.f, 0.f, 0.f, 0.f, 0.f, 0.f, 0.f};

    int e = rowStart[node];
    int end = rowStart[node + 1];
    for (; e + 3 < end; e += 4) {
        int s0 = csrSrc[e + 0];
        int s1 = csrSrc[e + 1];
        int s2 = csrSrc[e + 2];
        int s3 = csrSrc[e + 3];
        uint4 u0 = h16[(size_t)s0 * 8 + c];
        uint4 u1 = h16[(size_t)s1 * 8 + c];
        uint4 u2 = h16[(size_t)s2 * 8 + c];
        uint4 u3 = h16[(size_t)s3 * 8 + c];
        add8(a, u0); add8(a, u1); add8(a, u2); add8(a, u3);
    }
    for (; e < end; ++e) {
        uint4 u0 = h16[(size_t)csrSrc[e] * 8 + c];
        add8(a, u0);
    }

    unsigned d[4];
#pragma unroll
    for (int p = 0; p < 4; ++p)
        d[p] = (unsigned)f2b(a[2 * p]) | ((unsigned)f2b(a[2 * p + 1]) << 16);
    ((uint4*)aggB)[(size_t)node * 8 + c] = make_uint4(d[0], d[1], d[2], d[3]);
}

// ---------------------------------------------------------------------------
// MFMA matvec: out[n] = act( [aggB | self] @ [Wl;Wr]^T + bl )
// 128 nodes/block, 4 waves x 32 nodes. K=128 in 4 steps of 32.
// flags: bit0 = tanh, bit1 = bf16 output.
// ---------------------------------------------------------------------------
__global__ __launch_bounds__(256, 4) void matvec_mfma(
    const ushort* __restrict__ aggB, const ushort* __restrict__ hb,
    const ushort* __restrict__ wbuf, const float* __restrict__ bl,
    void* __restrict__ out, int n, int flags) {
    __shared__ float outT[128 * 68];   // 34 KB

    int t = threadIdx.x;
    int w = t >> 6;
    int l = t & 63;
    int quad = l >> 4;
    int lo = l & 15;
    int node0 = blockIdx.x * 128 + w * 32;

    f32x4 acc[2][4];
#pragma unroll
    for (int ot = 0; ot < 4; ++ot) {
        float bv = bl[ot * 16 + lo];
        f32x4 bvv = {bv, bv, bv, bv};
        acc[0][ot] = bvv;
        acc[1][ot] = bvv;
    }

#pragma unroll
    for (int s = 0; s < 4; ++s) {
        const ushort* hbase = (s < 2) ? aggB : hb;
        bf16x8 A[2];
#pragma unroll
        for (int mt = 0; mt < 2; ++mt) {
            size_t node = (size_t)node0 + mt * 16 + lo;
            A[mt] = *(const bf16x8*)(hbase + node * 64 + (s & 1) * 32 + quad * 8);
        }
#pragma unroll
        for (int ot = 0; ot < 4; ++ot) {
            bf16x8 B = *(const bf16x8*)(wbuf + (((s * 4 + ot) * 64) + l) * 8);
#pragma unroll
            for (int mt = 0; mt < 2; ++mt)
                acc[mt][ot] = __builtin_amdgcn_mfma_f32_16x16x32_bf16(
                    A[mt], B, acc[mt][ot], 0, 0, 0);
        }
    }

    // Epilogue: tanh + transpose via LDS (wave-private rows, no barrier)
#pragma unroll
    for (int mt = 0; mt < 2; ++mt) {
#pragma unroll
        for (int ot = 0; ot < 4; ++ot) {
            f32x4 v = acc[mt][ot];
            if (flags & 1) {
                v[0] = tanhf(v[0]); v[1] = tanhf(v[1]);
                v[2] = tanhf(v[2]); v[3] = tanhf(v[3]);
            }
            int row = w * 32 + mt * 16 + quad * 4;
            int col = ot * 16 + lo;
#pragma unroll
            for (int r = 0; r < 4; ++r)
                outT[(row + r) * 68 + col] = v[r];
        }
    }

    int row = w * 32 + (l >> 1);
    int node = blockIdx.x * 128 + row;
    if (node < n) {
        const float* srcp = &outT[row * 68 + (l & 1) * 32];
        if (flags & 2) {
            uint4* o8 = (uint4*)out;    // bf16 row = 8 uint4
#pragma unroll
            for (int q = 0; q < 4; ++q) {
                unsigned d[4];
#pragma unroll
                for (int p = 0; p < 4; ++p) {
                    float va = srcp[q * 8 + 2 * p];
                    float vb = srcp[q * 8 + 2 * p + 1];
                    d[p] = (unsigned)f2b(va) | ((unsigned)f2b(vb) << 16);
                }
                o8[(size_t)node * 8 + (l & 1) * 4 + q] = make_uint4(d[0], d[1], d[2], d[3]);
            }
        } else {
            float4* o16 = (float4*)out; // fp32 row = 16 float4
#pragma unroll
            for (int q = 0; q < 8; ++q) {
                float4 v = *(const float4*)(srcp + q * 4);
                o16[(size_t)node * 16 + (l & 1) * 8 + q] = v;
            }
        }
    }
}

// ---------------------------------------------------------------------------
// Launch
// ---------------------------------------------------------------------------
extern "C" void kernel_launch(void* const* d_in, const int* in_sizes, int n_in,
                              void* d_out, int out_size, void* d_ws, size_t ws_size,
                              hipStream_t stream) {
    const float* x      = (const float*)d_in[0];
    const int*   edges  = (const int*)d_in[1];
    const float* Wl_in  = (const float*)d_in[2];
    const float* bl_in  = (const float*)d_in[3];
    const float* Wr_in  = (const float*)d_in[4];
    const float* Wl_med = (const float*)d_in[5];
    const float* bl_med = (const float*)d_in[6];
    const float* Wr_med = (const float*)d_in[7];
    const float* Wl_out = (const float*)d_in[8];
    const float* bl_out = (const float*)d_in[9];
    const float* Wr_out = (const float*)d_in[10];

    const int N = in_sizes[0] / F;
    const int E = in_sizes[1] / 2;
    const int* src = edges;
    const int* dst = edges + E;

    const int nf  = (N + 127) >> 7;              // fine buckets (782)
    const int NB1 = (E + TILE1 - 1) / TILE1;     // bucketing tiles (147)
    const int NR  = nf * 128;                    // padded node count
    const int scanLen = nf * NB1;
    const int nbScan = (scanLen + SCAN_BLK - 1) / SCAN_BLK;

    // Workspace layout (16B-aligned chunks)
    ushort*  wbuf      = (ushort*)d_ws;                        // 3*8192 bf16
    ushort*  aggB      = wbuf + 3 * 8192;                      // NR*F bf16
    ushort*  xb        = aggB + (size_t)NR * F;                // NR*F bf16
    ushort*  hAb       = xb + (size_t)NR * F;                  // NR*F bf16
    ushort*  hBb       = hAb + (size_t)NR * F;                 // NR*F bf16
    int*     rowStart  = (int*)(hBb + (size_t)NR * F);         // NR+2
    int*     blockSums = rowStart + NR + 2;                    // nbScan (<=1024)
    int*     binMat    = blockSums + SCAN_BLK;                 // nf*NB1
    unsigned* stage2   = (unsigned*)(binMat + scanLen);        // E
    int*     csrSrc    = (int*)(stage2 + E);                   // E

    const int gather_blocks = NR / 32;          // NR*8/256
    const int prep_blocks = 12 + (N * F / 4 + 255) / 256;

    // Prep (weight B-frags + x->bf16)
    prep_kernel<<<prep_blocks, 256, 0, stream>>>(Wl_in, Wr_in, Wl_med, Wr_med,
                                                 Wl_out, Wr_out, wbuf, x, xb, N * F);

    // Single-level fine bucketing -> csrSrc + rowStart
    hist_kernel<<<NB1, 256, 0, stream>>>(dst, binMat, E, NB1, nf);
    scan_blocks_kernel<<<nbScan, SCAN_BLK, 0, stream>>>(binMat, blockSums, scanLen);
    scan_sums_kernel<<<1, SCAN_BLK, 0, stream>>>(blockSums, nbScan);
    scan_add_kernel<<<(scanLen + 255) / 256, 256, 0, stream>>>(binMat, blockSums, scanLen);
    scatter_kernel<<<NB1, 256, 0, stream>>>(src, dst, binMat, stage2, E, NB1, nf);
    phase2_kernel<<<nf, 256, 0, stream>>>(stage2, binMat, csrSrc, rowStart, E, NB1, nf);

    // Layer 1: xb -> hAb (tanh, bf16 out)
    gather_kernel<<<gather_blocks, 256, 0, stream>>>(xb, rowStart, csrSrc, aggB, NR);
    matvec_mfma<<<nf, 256, 0, stream>>>(aggB, xb, wbuf + 0,     bl_in,  hAb,   N, 3);
    // Layer 2: hAb -> hBb
    gather_kernel<<<gather_blocks, 256, 0, stream>>>(hAb, rowStart, csrSrc, aggB, NR);
    matvec_mfma<<<nf, 256, 0, stream>>>(aggB, hAb, wbuf + 8192, bl_med, hBb,   N, 3);
    // Layer 3: hBb -> hAb
    gather_kernel<<<gather_blocks, 256, 0, stream>>>(hBb, rowStart, csrSrc, aggB, NR);
    matvec_mfma<<<nf, 256, 0, stream>>>(aggB, hBb, wbuf + 8192, bl_med, hAb,   N, 3);
    // Layer 4: hAb -> d_out (no tanh, fp32 out)
    gather_kernel<<<gather_blocks, 256, 0, stream>>>(hAb, rowStart, csrSrc, aggB, NR);
    matvec_mfma<<<nf, 256, 0, stream>>>(aggB, hAb, wbuf + 16384, bl_out, d_out, N, 0);
}